// Round 8
// baseline (221.026 us; speedup 1.0000x reference)
//
#include <hip/hip_runtime.h>
#include <hip/hip_fp16.h>

#define NNODES 100000
#define NEG_SLOPE 0.2f
#define NBK 49          // buckets of 2048 nodes (dst>>11)
#define BKSHIFT 11
#define BKMASK 2047
#define BCAP 35328      // be[] slots/bucket; mean 32768, ~14 sigma slack
#define B1 4096         // edges per bin block

typedef _Float16 f16x8 __attribute__((ext_vector_type(8)));
typedef float f32x4 __attribute__((ext_vector_type(4)));

// ---------------- init ----------------

__global__ void k_init(int* __restrict__ gcur, int* __restrict__ offs, int N, int E) {
    int t = threadIdx.x;
    if (t < NBK) gcur[t] = t * BCAP;
    if (t == NBK) offs[N] = E;
}

// ---------------- bin: pack edges into coarse-bucket regions ----------------
// 4B packed entry (src<<11 | dst&2047); ~83-edge runs per (block,bucket) ->
// line-coalesced writes (round 7: 8B entries in 5-edge runs caused 58MB of
// amplified write traffic and a 75us latency-bound kernel).

__global__ __launch_bounds__(256) void k_bin(const int* __restrict__ src,
                                             const int* __restrict__ dst,
                                             int* __restrict__ gcur,
                                             int* __restrict__ be, int E) {
    __shared__ int lcnt[NBK], lbase[NBK], lcur[NBK];
    int t = threadIdx.x;
    int base = blockIdx.x * B1;
    if (t < NBK) lcnt[t] = 0;
    __syncthreads();
#pragma unroll
    for (int j = 0; j < B1 / 256; ++j) {
        int e = base + j * 256 + t;
        if (e < E) atomicAdd(&lcnt[dst[e] >> BKSHIFT], 1);
    }
    __syncthreads();
    if (t < NBK) { lbase[t] = atomicAdd(&gcur[t], lcnt[t]); lcur[t] = 0; }
    __syncthreads();
#pragma unroll
    for (int j = 0; j < B1 / 256; ++j) {
        int e = base + j * 256 + t;
        if (e < E) {
            int d = dst[e];
            int bk = d >> BKSHIFT;
            int p = lbase[bk] + atomicAdd(&lcur[bk], 1);
            be[p] = (src[e] << BKSHIFT) | (d & BKMASK);
        }
    }
}

// ---------------- fused: per-bucket scatter (blocks 0..48) + GEMM1 (rest) ----
// Scatter role: per-node LDS histogram over 2048 nodes, scan -> writes offs[]
// AND csr[] (sorted within a 128KB window, single-L2 locality). Only 49
// blocks; they hide under the 1563 gemm blocks.
// GEMM role: 64 rows/block, x & W^T staged f16 XOR-swizzled, 16x16x32 MFMA.

__global__ __launch_bounds__(256, 4) void k_gemm1sc(
    const float* __restrict__ x, const float* __restrict__ W,
    const float* __restrict__ al, const float* __restrict__ ar,
    __half* __restrict__ h, float* __restrict__ el, float* __restrict__ er,
    int N, const int* __restrict__ gcur, const int* __restrict__ be,
    int* __restrict__ offs, int* __restrict__ csr, int E) {

    __shared__ float4 SMEM[2048];   // 32KB, dual-purpose
    int t = threadIdx.x;

    if ((int)blockIdx.x < NBK) {    // ---- scatter role ----
        int* I = (int*)SMEM;
        int* cnt = I;               // 2048 per-node counters/cursors
        int* sb  = I + 2048;        // 2x256 scan buffer
        // I[2560] = rbeg
        int b = blockIdx.x;
        int mycnt = gcur[b] - b * BCAP;
        int ebase = b * BCAP;

        for (int i = t; i < 2048; i += 256) cnt[i] = 0;
        if (t == 0) I[2560] = 0;
        __syncthreads();
        for (int i = t; i < mycnt; i += 256) atomicAdd(&cnt[be[ebase + i] & BKMASK], 1);
        if (t < 64) {               // rbeg = sum of previous bucket counts
            int v = (t < b) ? gcur[t] - t * BCAP : 0;
#pragma unroll
            for (int o = 32; o; o >>= 1) v += __shfl_xor(v, o);
            if (t == 0) I[2560] = v;
        }
        __syncthreads();

        int loc[8]; int s = 0;
#pragma unroll
        for (int i = 0; i < 8; ++i) { loc[i] = s; s += cnt[8 * t + i]; }
        sb[t] = s;
        __syncthreads();
        int pi = 0;
        for (int d = 1; d < 256; d <<= 1) {
            int po = pi ^ 1;
            sb[po * 256 + t] = sb[pi * 256 + t] + (t >= d ? sb[pi * 256 + t - d] : 0);
            pi = po;
            __syncthreads();
        }
        int bas = I[2560] + sb[pi * 256 + t] - s;

        int node0 = (b << BKSHIFT) + 8 * t;
#pragma unroll
        for (int i = 0; i < 8; ++i) {
            int node = node0 + i;
            if (node < N) offs[node] = bas + loc[i];
        }
        __syncthreads();            // all cnt reads done (covered by scan syncs)
#pragma unroll
        for (int i = 0; i < 8; ++i) cnt[8 * t + i] = bas + loc[i];
        __syncthreads();
        for (int i = t; i < mycnt; i += 256) {
            int v = be[ebase + i];
            int p = atomicAdd(&cnt[v & BKMASK], 1);
            csr[p] = v >> BKSHIFT;
        }
        return;
    }

    // ---- GEMM role ----
    char* A  = (char*)SMEM;          // 16KB: 64 rows x 256B f16 swz
    char* Bw = (char*)SMEM + 16384;  // 16KB: 64 cols x 256B f16 swz
    int row0 = ((int)blockIdx.x - NBK) * 64;

    for (int i = t; i < 2048; i += 256) {
        int r = i >> 5, c4 = i & 31;
        int rr = row0 + r; if (rr > N - 1) rr = N - 1;
        float4 v = *(const float4*)(x + (size_t)rr * 128 + c4 * 4);
        int byte = r * 256 + ((c4 * 8) ^ ((r & 7) << 4));
        *(__half2*)(A + byte)     = __floats2half2_rn(v.x, v.y);
        *(__half2*)(A + byte + 4) = __floats2half2_rn(v.z, v.w);
    }
    for (int i = t; i < 2048; i += 256) {
        int k = i >> 4, c4 = (i & 15) * 4;
        float4 v = *(const float4*)(W + k * 64 + c4);
        int kb = k * 2;
        *(__half*)(Bw + (c4 + 0) * 256 + (kb ^ (((c4 + 0) & 7) << 4))) = __float2half(v.x);
        *(__half*)(Bw + (c4 + 1) * 256 + (kb ^ (((c4 + 1) & 7) << 4))) = __float2half(v.y);
        *(__half*)(Bw + (c4 + 2) * 256 + (kb ^ (((c4 + 2) & 7) << 4))) = __float2half(v.z);
        *(__half*)(Bw + (c4 + 3) * 256 + (kb ^ (((c4 + 3) & 7) << 4))) = __float2half(v.w);
    }
    __syncthreads();

    int w = t >> 6, l = t & 63, g = l >> 4, c = l & 15;
    int swz = (c & 7) << 4;
    const char* Ar = A + (w * 16 + c) * 256;

    f32x4 acc[4];
#pragma unroll
    for (int t2 = 0; t2 < 4; ++t2) acc[t2] = (f32x4){0.f, 0.f, 0.f, 0.f};
#pragma unroll
    for (int kk = 0; kk < 4; ++kk) {
        int kb = kk * 64 + g * 16;
        f16x8 av = *(const f16x8*)(Ar + (kb ^ swz));
#pragma unroll
        for (int t2 = 0; t2 < 4; ++t2) {
            f16x8 bv = *(const f16x8*)(Bw + (t2 * 16 + c) * 256 + (kb ^ swz));
            acc[t2] = __builtin_amdgcn_mfma_f32_16x16x32_f16(av, bv, acc[t2], 0, 0, 0);
        }
    }

    float alv[4], arv[4];
#pragma unroll
    for (int t2 = 0; t2 < 4; ++t2) { alv[t2] = al[t2 * 16 + c]; arv[t2] = ar[t2 * 16 + c]; }
#pragma unroll
    for (int r = 0; r < 4; ++r) {
        float e1 = 0.f, e2 = 0.f;
#pragma unroll
        for (int t2 = 0; t2 < 4; ++t2) {
            e1 = fmaf(acc[t2][r], alv[t2], e1);
            e2 = fmaf(acc[t2][r], arv[t2], e2);
        }
#pragma unroll
        for (int o = 1; o < 16; o <<= 1) { e1 += __shfl_xor(e1, o); e2 += __shfl_xor(e2, o); }
        int row = row0 + w * 16 + 4 * g + r;
        if (row < N) {
            if (c == 0) { el[row] = e1; er[row] = e2; }
#pragma unroll
            for (int t2 = 0; t2 < 4; ++t2)
                h[(size_t)row * 64 + t2 * 16 + c] = __float2half(acc[t2][r]);
        }
    }
}

// ---------------- GEMM2 (MFMA, f16 in/out) ----------------

__global__ __launch_bounds__(256, 4) void k_gemm2(
    const __half* __restrict__ xin, const float* __restrict__ W,
    const float* __restrict__ al, const float* __restrict__ ar,
    __half* __restrict__ h, float* __restrict__ el, float* __restrict__ er, int N) {

    __shared__ float4 AlR[512];
    __shared__ float4 WtR[512];
    char* A = (char*)AlR;
    char* Bw = (char*)WtR;
    int tid = threadIdx.x;
    int row0 = blockIdx.x * 64;

    for (int i = tid; i < 512; i += 256) {
        int r = i >> 3, o = i & 7;
        int rr = row0 + r; if (rr > N - 1) rr = N - 1;
        float4 v = *(const float4*)(xin + (size_t)rr * 64 + o * 8);
        *(float4*)(A + r * 128 + ((o * 16) ^ ((r & 7) << 4))) = v;
    }
    for (int i = tid; i < 1024; i += 256) {
        int k = i >> 4, c4 = (i & 15) * 4;
        float4 v = *(const float4*)(W + k * 64 + c4);
        int kb = k * 2;
        *(__half*)(Bw + (c4 + 0) * 128 + (kb ^ (((c4 + 0) & 7) << 4))) = __float2half(v.x);
        *(__half*)(Bw + (c4 + 1) * 128 + (kb ^ (((c4 + 1) & 7) << 4))) = __float2half(v.y);
        *(__half*)(Bw + (c4 + 2) * 128 + (kb ^ (((c4 + 2) & 7) << 4))) = __float2half(v.z);
        *(__half*)(Bw + (c4 + 3) * 128 + (kb ^ (((c4 + 3) & 7) << 4))) = __float2half(v.w);
    }
    __syncthreads();

    int w = tid >> 6, l = tid & 63, g = l >> 4, c = l & 15;
    int swz = (c & 7) << 4;
    const char* Ar = A + (w * 16 + c) * 128;

    f32x4 acc[4];
#pragma unroll
    for (int t2 = 0; t2 < 4; ++t2) acc[t2] = (f32x4){0.f, 0.f, 0.f, 0.f};
#pragma unroll
    for (int kk = 0; kk < 2; ++kk) {
        int kb = kk * 64 + g * 16;
        f16x8 av = *(const f16x8*)(Ar + (kb ^ swz));
#pragma unroll
        for (int t2 = 0; t2 < 4; ++t2) {
            f16x8 bv = *(const f16x8*)(Bw + (t2 * 16 + c) * 128 + (kb ^ swz));
            acc[t2] = __builtin_amdgcn_mfma_f32_16x16x32_f16(av, bv, acc[t2], 0, 0, 0);
        }
    }

    float alv[4], arv[4];
#pragma unroll
    for (int t2 = 0; t2 < 4; ++t2) { alv[t2] = al[t2 * 16 + c]; arv[t2] = ar[t2 * 16 + c]; }
#pragma unroll
    for (int r = 0; r < 4; ++r) {
        float e1 = 0.f, e2 = 0.f;
#pragma unroll
        for (int t2 = 0; t2 < 4; ++t2) {
            e1 = fmaf(acc[t2][r], alv[t2], e1);
            e2 = fmaf(acc[t2][r], arv[t2], e2);
        }
#pragma unroll
        for (int o = 1; o < 16; o <<= 1) { e1 += __shfl_xor(e1, o); e2 += __shfl_xor(e2, o); }
        int row = row0 + w * 16 + 4 * g + r;
        if (row < N) {
            if (c == 0) { el[row] = e1; er[row] = e2; }
#pragma unroll
            for (int t2 = 0; t2 < 4; ++t2)
                h[(size_t)row * 64 + t2 * 16 + c] = __float2half(acc[t2][r]);
        }
    }
}

// ---------------- edge softmax + aggregation ----------------

__device__ inline float2 h2_to_f2(float bits) {
    return __half22float2(__builtin_bit_cast(__half2, bits));
}

template <bool OUT_HALF>
__global__ __launch_bounds__(256) void k_agg(const __half* __restrict__ h,
                                             const float* __restrict__ el,
                                             const float* __restrict__ er,
                                             const float* __restrict__ b,
                                             const int* __restrict__ offs,
                                             const int* __restrict__ csr_src,
                                             void* __restrict__ outp, int N, int relu) {
    int wave = threadIdx.x >> 6, lane = threadIdx.x & 63;
    int n = blockIdx.x * 4 + wave;
    if (n >= N) return;

    int beg = offs[n], end = offs[n + 1];
    int deg = end - beg;
    float ern = er[n];

    int g = lane >> 4;
    int fl = lane & 15;
    float4 accv = make_float4(0.f, 0.f, 0.f, 0.f);
    const size_t foff = 4 * (size_t)fl;

    if (deg <= 64) {
        int sidx = 0;
        float e = -1e30f;
        if (lane < deg) {
            sidx = csr_src[beg + lane];
            e = el[sidx] + ern;
            e = e > 0.f ? e : NEG_SLOPE * e;
        }
        float m = e;
#pragma unroll
        for (int o = 32; o; o >>= 1) m = fmaxf(m, __shfl_xor(m, o));
        float p = (lane < deg) ? __expf(e - m) : 0.f;
        float s = p;
#pragma unroll
        for (int o = 32; o; o >>= 1) s += __shfl_xor(s, o);
        float a = p * (1.f / fmaxf(s, 1e-9f));

        int iters = (deg + 3) >> 2;   // wave-uniform (shuffle safety, round-3 bug)
        int pair = iters >> 1;
        int i = g;
        for (int t2 = 0; t2 < pair; ++t2, i += 8) {
            int s0 = __shfl(sidx, i), s1 = __shfl(sidx, i + 4);
            float w0 = __shfl(a, i), w1 = __shfl(a, i + 4);
            float2 r0 = *(const float2*)(h + (size_t)s0 * 64 + foff);
            float2 r1 = *(const float2*)(h + (size_t)s1 * 64 + foff);
            float2 f00 = h2_to_f2(r0.x), f01 = h2_to_f2(r0.y);
            float2 f10 = h2_to_f2(r1.x), f11 = h2_to_f2(r1.y);
            accv.x = fmaf(w0, f00.x, accv.x); accv.y = fmaf(w0, f00.y, accv.y);
            accv.z = fmaf(w0, f01.x, accv.z); accv.w = fmaf(w0, f01.y, accv.w);
            accv.x = fmaf(w1, f10.x, accv.x); accv.y = fmaf(w1, f10.y, accv.y);
            accv.z = fmaf(w1, f11.x, accv.z); accv.w = fmaf(w1, f11.y, accv.w);
        }
        if (iters & 1) {
            int s0 = __shfl(sidx, i);
            float w0 = __shfl(a, i);
            float2 r0 = *(const float2*)(h + (size_t)s0 * 64 + foff);
            float2 f00 = h2_to_f2(r0.x), f01 = h2_to_f2(r0.y);
            accv.x = fmaf(w0, f00.x, accv.x); accv.y = fmaf(w0, f00.y, accv.y);
            accv.z = fmaf(w0, f01.x, accv.z); accv.w = fmaf(w0, f01.y, accv.w);
        }
    } else {
        float m = -1e30f;
        for (int i = beg + lane; i < end; i += 64) {
            float e = el[csr_src[i]] + ern;
            e = e > 0.f ? e : NEG_SLOPE * e;
            m = fmaxf(m, e);
        }
#pragma unroll
        for (int o = 32; o; o >>= 1) m = fmaxf(m, __shfl_xor(m, o));
        float s = 0.f;
        for (int i = beg + lane; i < end; i += 64) {
            float e = el[csr_src[i]] + ern;
            e = e > 0.f ? e : NEG_SLOPE * e;
            s += __expf(e - m);
        }
#pragma unroll
        for (int o = 32; o; o >>= 1) s += __shfl_xor(s, o);
        float inv = 1.f / fmaxf(s, 1e-9f);

        for (int i = g; i < deg; i += 4) {
            int s0 = csr_src[beg + i];
            float e = el[s0] + ern;
            e = e > 0.f ? e : NEG_SLOPE * e;
            float w0 = __expf(e - m) * inv;
            float2 r0 = *(const float2*)(h + (size_t)s0 * 64 + foff);
            float2 f00 = h2_to_f2(r0.x), f01 = h2_to_f2(r0.y);
            accv.x = fmaf(w0, f00.x, accv.x); accv.y = fmaf(w0, f00.y, accv.y);
            accv.z = fmaf(w0, f01.x, accv.z); accv.w = fmaf(w0, f01.y, accv.w);
        }
    }

#pragma unroll
    for (int o = 16; o <= 32; o <<= 1) {
        accv.x += __shfl_xor(accv.x, o);
        accv.y += __shfl_xor(accv.y, o);
        accv.z += __shfl_xor(accv.z, o);
        accv.w += __shfl_xor(accv.w, o);
    }

    if (lane < 16) {
        float4 bv = *(const float4*)(b + foff);
        float ox = accv.x + bv.x, oy = accv.y + bv.y;
        float oz = accv.z + bv.z, ow = accv.w + bv.w;
        if (relu) {
            ox = fmaxf(ox, 0.f); oy = fmaxf(oy, 0.f);
            oz = fmaxf(oz, 0.f); ow = fmaxf(ow, 0.f);
        }
        if (OUT_HALF) {
            __half* oh = (__half*)outp + (size_t)n * 64 + foff;
            *(__half2*)(oh)     = __floats2half2_rn(ox, oy);
            *(__half2*)(oh + 2) = __floats2half2_rn(oz, ow);
        } else {
            *(float4*)((float*)outp + (size_t)n * 64 + foff) = make_float4(ox, oy, oz, ow);
        }
    }
}

// ---------------- launch ----------------

extern "C" void kernel_launch(void* const* d_in, const int* in_sizes, int n_in,
                              void* d_out, int out_size, void* d_ws, size_t ws_size,
                              hipStream_t stream) {
    const float* x   = (const float*)d_in[0];
    const int*   src = (const int*)d_in[1];
    const int*   dst = (const int*)d_in[2];
    const float* W1  = (const float*)d_in[3];
    const float* al1 = (const float*)d_in[4];
    const float* ar1 = (const float*)d_in[5];
    const float* b1  = (const float*)d_in[6];
    const float* W2  = (const float*)d_in[7];
    const float* al2 = (const float*)d_in[8];
    const float* ar2 = (const float*)d_in[9];
    const float* b2  = (const float*)d_in[10];
    float* out = (float*)d_out;

    const int N = NNODES;
    const int E = in_sizes[1];

    __half* h    = (__half*)d_ws;                      // 12.8MB
    __half* hmid = h + (size_t)N * 64;                 // 12.8MB
    int*    be   = (int*)(hmid + (size_t)N * 64);      // NBK*BCAP (6.9MB)
    int*    csr  = be + (size_t)NBK * BCAP;            // E (6.4MB)
    float*  el   = (float*)(csr + E);                  // N
    float*  er   = el + N;                             // N
    int*    offs = (int*)(er + N);                     // N+1
    int*    gcur = offs + N + 1;                       // NBK

    int nbBin = (E + B1 - 1) / B1;            // 391
    int nbG   = (N + 63) / 64;                // 1563
    int nbR   = (N + 3) / 4;                  // 25000

    k_init<<<1, 64, 0, stream>>>(gcur, offs, N, E);
    k_bin<<<nbBin, 256, 0, stream>>>(src, dst, gcur, be, E);
    // scatter (49 blocks) fused under the layer-1 MFMA GEMM (1563 blocks)
    k_gemm1sc<<<NBK + nbG, 256, 0, stream>>>(x, W1, al1, ar1, h, el, er, N,
                                             gcur, be, offs, csr, E);
    k_agg<true><<<nbR, 256, 0, stream>>>(h, el, er, b1, offs, csr, hmid, N, 1);
    k_gemm2<<<nbG, 256, 0, stream>>>(hmid, W2, al2, ar2, h, el, er, N);
    k_agg<false><<<nbR, 256, 0, stream>>>(h, el, er, b2, offs, csr, out, N, 0);
}